// Round 2
// baseline (5142.373 us; speedup 1.0000x reference)
//
#include <hip/hip_runtime.h>
#include <math.h>

// LorentzTemporalBlock — fp32 baseline, per-batch chunked to fit workspace.
// B=8, T=512, J=26, D=256, H=8, DH=32, HID=1024. RB = T*J = 13312 rows/batch.
// Per batch b:
//  k_t    : t = logmap0(expmap0(LN(logmap0(x))))                  -> bufA
//  k_gemm : pq = elu(t@Wq+bq)+1 -> bufB ; pk -> bufC ; v -> bufD
//  k_kv   : kv[jh][32][32], ksum[jh][32] from pk,v                -> kvb/ksb
//  k_attn : attn = (pq@kv)/(pq@ksum+eps)                          -> bufC
//  k_gemm : o = attn@Wo+bo                                        -> bufD
//  k_u2   : u2 = LN(logmap0(lorentz_residual(x, expmap0(o))))     -> bufA
//  MLP x4 chunks (3328 rows): hid=gelu(u2@W1+bf1) -> bufB ; f -> bufC
//  k_out  : out = expmap0(f)
// Peak ws: 4*13312*256 + 208*1056 floats ≈ 55.4 MB (was 443 MB -> ws OOB abort).

#define EPSF 1e-6f
#define B_ 8
#define T_ 512
#define J_ 26
#define D_ 256
#define H_ 8
#define DH_ 32
#define HID_ 1024
#define NP1 257
#define RB_ (T_*J_)      // 13312 rows per batch, = 64*208

// ---------- block-wide sum over 256 threads ----------
__device__ __forceinline__ float block_reduce_sum(float v, float* sbuf) {
#pragma unroll
  for (int off = 32; off > 0; off >>= 1) v += __shfl_down(v, off, 64);
  int wid = threadIdx.x >> 6, lane = threadIdx.x & 63;
  __syncthreads();              // protect sbuf reuse across calls
  if (lane == 0) sbuf[wid] = v;
  __syncthreads();
  return sbuf[0] + sbuf[1] + sbuf[2] + sbuf[3];
}

// ---------- kernel 1: t = logmap0(expmap0(LN(logmap0(x)))) ----------
__global__ __launch_bounds__(256) void k_t(const float* __restrict__ x,
                                           const float* __restrict__ g1,
                                           const float* __restrict__ beta1,
                                           float* __restrict__ t) {
  __shared__ float sbuf[4];
  int r = blockIdx.x;
  int tid = threadIdx.x;
  const float* xr = x + (size_t)r * NP1;
  float xs = xr[1 + tid];
  float ss = block_reduce_sum(xs * xs, sbuf);
  float n1 = fmaxf(sqrtf(ss), EPSF);
  float x0 = fmaxf(xr[0], 1.0f + 1e-7f);
  float lm = acoshf(x0) * xs / n1;
  float mean = block_reduce_sum(lm, sbuf) * (1.0f/256.0f);
  float d = lm - mean;
  float var = block_reduce_sum(d*d, sbuf) * (1.0f/256.0f);
  float u = d * rsqrtf(var + 1e-5f) * g1[tid] + beta1[tid];
  float un = block_reduce_sum(u*u, sbuf);
  float nu = fmaxf(sqrtf(un), EPSF);
  float ch = coshf(nu), sh = sinhf(nu);
  float xs2 = sh * u / nu;
  float ss2 = block_reduce_sum(xs2*xs2, sbuf);
  float n2 = fmaxf(sqrtf(ss2), EPSF);
  float x0c = fmaxf(ch, 1.0f + 1e-7f);
  t[(size_t)r * D_ + tid] = acoshf(x0c) * xs2 / n2;
}

// ---------- generic tiled fp32 GEMM: C = act(A@W + b) ----------
// A: MxK row-major, W: KxN row-major. M%64==0, N%64==0, K%32==0.
// act: 0=none, 1=elu+1, 2=gelu(tanh approx)
#define BM 64
#define BN 64
#define BKK 32
__global__ __launch_bounds__(256) void k_gemm(const float* __restrict__ A,
                                              const float* __restrict__ W,
                                              const float* __restrict__ bias,
                                              float* __restrict__ Cout,
                                              int M, int N, int K, int act) {
  __shared__ float As[BKK][BM + 4];
  __shared__ float Ws[BKK][BN];
  int tid = threadIdx.x;
  int tx = tid & 15, ty = tid >> 4;
  int m0 = blockIdx.x * BM, n0 = blockIdx.y * BN;
  float acc[4][4] = {};
  int ra = tid >> 3;            // 0..31
  int ca = (tid & 7) << 2;      // 0..28
  int rw = tid >> 4;            // 0..15
  int cw = (tid & 15) << 2;     // 0..60

  for (int k0 = 0; k0 < K; k0 += BKK) {
    float4 a0 = *(const float4*)&A[(size_t)(m0 + ra) * K + k0 + ca];
    float4 a1 = *(const float4*)&A[(size_t)(m0 + ra + 32) * K + k0 + ca];
    As[ca+0][ra] = a0.x; As[ca+1][ra] = a0.y; As[ca+2][ra] = a0.z; As[ca+3][ra] = a0.w;
    As[ca+0][ra+32] = a1.x; As[ca+1][ra+32] = a1.y; As[ca+2][ra+32] = a1.z; As[ca+3][ra+32] = a1.w;
    float4 w0 = *(const float4*)&W[(size_t)(k0 + rw) * N + n0 + cw];
    float4 w1 = *(const float4*)&W[(size_t)(k0 + rw + 16) * N + n0 + cw];
    *(float4*)&Ws[rw][cw] = w0;
    *(float4*)&Ws[rw+16][cw] = w1;
    __syncthreads();
#pragma unroll
    for (int kk = 0; kk < BKK; ++kk) {
      float4 av = *(const float4*)&As[kk][ty << 2];
      float4 wv = *(const float4*)&Ws[kk][tx << 2];
      float a4[4] = {av.x, av.y, av.z, av.w};
      float w4[4] = {wv.x, wv.y, wv.z, wv.w};
#pragma unroll
      for (int i = 0; i < 4; ++i)
#pragma unroll
        for (int j = 0; j < 4; ++j)
          acc[i][j] = fmaf(a4[i], w4[j], acc[i][j]);
    }
    __syncthreads();
  }

#pragma unroll
  for (int i = 0; i < 4; ++i) {
    int m = m0 + (ty << 2) + i;
#pragma unroll
    for (int j = 0; j < 4; ++j) {
      int n = n0 + (tx << 2) + j;
      float v = acc[i][j] + bias[n];
      if (act == 1) v = (v > 0.0f) ? v + 1.0f : expf(v);          // elu(x)+1
      else if (act == 2) {                                         // gelu tanh
        float x3 = v * v * v;
        v = 0.5f * v * (1.0f + tanhf(0.7978845608028654f * (v + 0.044715f * x3)));
      }
      Cout[(size_t)m * N + n] = v;
    }
  }
}

// ---------- kernel 3 (per-batch): kv + ksum per (j,h) ----------
__global__ __launch_bounds__(256) void k_kv(const float* __restrict__ pk,
                                            const float* __restrict__ v,
                                            float* __restrict__ kv,
                                            float* __restrict__ ksum) {
  __shared__ float spk[8][DH_];
  __shared__ float sv[8][DH_];
  int blk = blockIdx.x;          // j*H + h, 0..207
  int h = blk & 7;
  int j = blk >> 3;
  int tid = threadIdx.x;
  int tt = tid >> 5, dl = tid & 31;
  int dd = tid & 31, k0 = tid >> 5;
  float acc[4] = {0.f, 0.f, 0.f, 0.f};
  float ks = 0.f;
  for (int t0 = 0; t0 < T_; t0 += 8) {
    size_t row = (size_t)(t0 + tt) * J_ + j;
    spk[tt][dl] = pk[row * D_ + h * DH_ + dl];
    sv[tt][dl]  = v [row * D_ + h * DH_ + dl];
    __syncthreads();
#pragma unroll
    for (int q = 0; q < 8; ++q) {
      float vv = sv[q][dd];
#pragma unroll
      for (int m = 0; m < 4; ++m)
        acc[m] = fmaf(spk[q][k0 + (m << 3)], vv, acc[m]);
    }
    if (tid < 32) {
#pragma unroll
      for (int q = 0; q < 8; ++q) ks += spk[q][tid];
    }
    __syncthreads();
  }
#pragma unroll
  for (int m = 0; m < 4; ++m)
    kv[(size_t)blk * (DH_*DH_) + (size_t)(k0 + (m << 3)) * DH_ + dd] = acc[m];
  if (tid < 32) ksum[(size_t)blk * DH_ + tid] = ks;
}

// ---------- kernel 4 (per-batch): attn = (pq @ kv) / (pq @ ksum + eps) ----------
__global__ __launch_bounds__(256) void k_attn(const float* __restrict__ pq,
                                              const float* __restrict__ kv,
                                              const float* __restrict__ ksum,
                                              float* __restrict__ attn) {
  __shared__ float spq[D_];
  int r = blockIdx.x, tid = threadIdx.x;   // r = local row, 0..13311
  spq[tid] = pq[(size_t)r * D_ + tid];
  __syncthreads();
  int j = r % J_;
  int h = tid >> 5, dd = tid & 31;
  int jh = j * H_ + h;
  const float* kvp = kv + (size_t)jh * (DH_*DH_);
  const float* ksp = ksum + (size_t)jh * DH_;
  float num = 0.f, den = 0.f;
#pragma unroll
  for (int k = 0; k < DH_; ++k) {
    float p = spq[(h << 5) + k];
    num = fmaf(p, kvp[k * DH_ + dd], num);
    den = fmaf(p, ksp[k], den);
  }
  attn[(size_t)r * D_ + tid] = num / (den + EPSF);
}

// ---------- kernel 6: u2 = LN(logmap0(lorentz_residual(x, expmap0(o)))) ----------
__global__ __launch_bounds__(256) void k_u2(const float* __restrict__ o,
                                            const float* __restrict__ x,
                                            const float* __restrict__ g2,
                                            const float* __restrict__ beta2,
                                            float* __restrict__ u2) {
  __shared__ float sbuf[4];
  int r = blockIdx.x, tid = threadIdx.x;
  const float* xr = x + (size_t)r * NP1;
  float ov = o[(size_t)r * D_ + tid];
  float so = block_reduce_sum(ov * ov, sbuf);
  float no = fmaxf(sqrtf(so), EPSF);
  float ch = coshf(no), sh = sinhf(no);
  float zi = sh * ov / no;
  float mi = xr[1 + tid] + zi;
  float m0 = xr[0] + ch;
  float ssm = block_reduce_sum(mi * mi, sbuf);
  float denom = sqrtf(fmaxf(m0 * m0 - ssm, EPSF));
  float hi = mi / denom;
  float h0 = m0 / denom;
  float h0c = fmaxf(h0, 1.0f + 1e-7f);
  float sh2 = block_reduce_sum(hi * hi, sbuf);
  float nh = fmaxf(sqrtf(sh2), EPSF);
  float lm = acoshf(h0c) * hi / nh;
  float mean = block_reduce_sum(lm, sbuf) * (1.0f/256.0f);
  float d = lm - mean;
  float var = block_reduce_sum(d * d, sbuf) * (1.0f/256.0f);
  u2[(size_t)r * D_ + tid] = d * rsqrtf(var + 1e-5f) * g2[tid] + beta2[tid];
}

// ---------- kernel 9: out = expmap0(f) ----------
__global__ __launch_bounds__(256) void k_out(const float* __restrict__ f,
                                             float* __restrict__ out) {
  __shared__ float sbuf[4];
  int r = blockIdx.x, tid = threadIdx.x;
  float fv = f[(size_t)r * D_ + tid];
  float ss = block_reduce_sum(fv * fv, sbuf);
  float n = fmaxf(sqrtf(ss), EPSF);
  float sh = sinhf(n);
  if (tid == 0) out[(size_t)r * NP1] = coshf(n);
  out[(size_t)r * NP1 + 1 + tid] = sh * fv / n;
}

extern "C" void kernel_launch(void* const* d_in, const int* in_sizes, int n_in,
                              void* d_out, int out_size, void* d_ws, size_t ws_size,
                              hipStream_t stream) {
  const float* x     = (const float*)d_in[0];
  const float* g1    = (const float*)d_in[1];
  const float* beta1 = (const float*)d_in[2];
  const float* Wq    = (const float*)d_in[3];
  const float* Wk    = (const float*)d_in[4];
  const float* Wv    = (const float*)d_in[5];
  const float* Wo    = (const float*)d_in[6];
  const float* bq    = (const float*)d_in[7];
  const float* bk    = (const float*)d_in[8];
  const float* bv    = (const float*)d_in[9];
  const float* bo    = (const float*)d_in[10];
  const float* g2    = (const float*)d_in[11];
  const float* beta2 = (const float*)d_in[12];
  const float* W1    = (const float*)d_in[13];
  const float* bf1   = (const float*)d_in[14];
  const float* W2    = (const float*)d_in[15];
  const float* bf2   = (const float*)d_in[16];
  float* out = (float*)d_out;
  float* ws  = (float*)d_ws;

  const size_t RB2 = (size_t)RB_ * D_;         // 3,407,872 floats (13.6 MB)
  float* bufA = ws;
  float* bufB = ws + RB2;                      // also holds 3328x1024 MLP hid
  float* bufC = ws + 2 * RB2;
  float* bufD = ws + 3 * RB2;
  float* kvb  = ws + 4 * RB2;                  // 208*1024
  float* ksb  = kvb + (size_t)(J_*H_) * (DH_*DH_);   // 208*32

  const int Rc = RB_ / 4;                      // 3328 MLP rows per chunk

  for (int b = 0; b < B_; ++b) {
    const float* xb = x + (size_t)b * RB_ * NP1;
    float* outb = out + (size_t)b * RB_ * NP1;

    k_t<<<RB_, 256, 0, stream>>>(xb, g1, beta1, bufA);

    dim3 gqkv(RB_ / BM, D_ / BN);              // (208, 4)
    k_gemm<<<gqkv, 256, 0, stream>>>(bufA, Wq, bq, bufB, RB_, D_, D_, 1);
    k_gemm<<<gqkv, 256, 0, stream>>>(bufA, Wk, bk, bufC, RB_, D_, D_, 1);
    k_gemm<<<gqkv, 256, 0, stream>>>(bufA, Wv, bv, bufD, RB_, D_, D_, 0);

    k_kv<<<J_ * H_, 256, 0, stream>>>(bufC, bufD, kvb, ksb);
    k_attn<<<RB_, 256, 0, stream>>>(bufB, kvb, ksb, bufC);

    k_gemm<<<gqkv, 256, 0, stream>>>(bufC, Wo, bo, bufD, RB_, D_, D_, 0);
    k_u2<<<RB_, 256, 0, stream>>>(bufD, xb, g2, beta2, bufA);

    for (int c = 0; c < 4; ++c) {
      k_gemm<<<dim3(Rc / BM, HID_ / BN), 256, 0, stream>>>(
          bufA + (size_t)c * Rc * D_, W1, bf1, bufB, Rc, HID_, D_, 2);
      k_gemm<<<dim3(Rc / BM, D_ / BN), 256, 0, stream>>>(
          bufB, W2, bf2, bufC + (size_t)c * Rc * D_, Rc, D_, HID_, 0);
    }

    k_out<<<RB_, 256, 0, stream>>>(bufC, outb);
  }
}

// Round 3
// 1632.698 us; speedup vs baseline: 3.1496x; 3.1496x over previous
//
#include <hip/hip_runtime.h>
#include <hip/hip_bf16.h>
#include <math.h>

// LorentzTemporalBlock — bf16 MFMA GEMMs + fp32 elementwise.
// B=8,T=512,J=26,D=256,H=8,DH=32,HID=1024. R = 106496 rows (= 832*128).
// Full-R pipeline (no batch loop), 13 launches:
//  6x k_wconv : W fp32 [K][N] -> bf16 transposed [N][K]
//  k_t   : t = logmap0(expmap0(LN(logmap0(x))))  fp32 math -> bf16   -> tb
//  k_mm  : pq=elu+1 -> qb ; pk -> kb ; v -> vb   (bf16 out)
//  k_kv  : kv[bjh][32][32], ksum (fp32 accum from bf16)
//  k_attn: attn=(pq@kv)/(pq@ksum+eps) -> kb (bf16)
//  k_mm  : o = attn@Wo+bo -> vb (bf16)
//  k_u2  : u2 = LN(logmap0(lorentz_res(x, expmap0(o)))) -> tb (bf16)
//  2 MLP chunks: k_mm hid=gelu(u2@W1) (bf16) ; k_mm f=hid@W2 (fp32!) -> f
//  k_out : out = expmap0(f)
// f stays fp32: expmap0 amplifies ||f|| errors by sinh(13)~2e5; everything
// upstream washes through scale-invariant layernorms (direction-only).
// ws: weights 1.5MB + kv 7MB + 4x54.5MB bf16 acts + 109MB hid; f(fp32)
// aliases qb+kb. Total ~336MB < ~418MiB ws.

#define EPSF 1e-6f
#define B_ 8
#define T_ 512
#define J_ 26
#define D_ 256
#define H_ 8
#define DH_ 32
#define HID_ 1024
#define NP1 257
#define R_ (B_*T_*J_)    // 106496

typedef float  f32x4  __attribute__((ext_vector_type(4)));
typedef short  s16x8  __attribute__((ext_vector_type(8)));

// ---------- async global->LDS 16B ----------
__device__ __forceinline__ void async16(const void* g, void* l) {
  __builtin_amdgcn_global_load_lds(
      (const __attribute__((address_space(1))) unsigned int*)g,
      (__attribute__((address_space(3))) unsigned int*)l, 16, 0, 0);
}

// ---------- block-wide sum over 256 threads ----------
__device__ __forceinline__ float block_reduce_sum(float v, float* sbuf) {
#pragma unroll
  for (int off = 32; off > 0; off >>= 1) v += __shfl_down(v, off, 64);
  int wid = threadIdx.x >> 6, lane = threadIdx.x & 63;
  __syncthreads();
  if (lane == 0) sbuf[wid] = v;
  __syncthreads();
  return sbuf[0] + sbuf[1] + sbuf[2] + sbuf[3];
}

// ---------- weight transpose+convert: W fp32 [K][N] -> Wt bf16 [N][K] ----------
__global__ __launch_bounds__(256) void k_wconv(const float* __restrict__ W,
                                               __hip_bfloat16* __restrict__ Wt,
                                               int K, int N) {
  __shared__ float tile[32][33];
  int n0 = blockIdx.x * 32, k0 = blockIdx.y * 32;
  int tx = threadIdx.x, ty = threadIdx.y;   // (32,8)
#pragma unroll
  for (int i = ty; i < 32; i += 8) tile[i][tx] = W[(size_t)(k0 + i) * N + n0 + tx];
  __syncthreads();
#pragma unroll
  for (int i = ty; i < 32; i += 8)
    Wt[(size_t)(n0 + i) * K + k0 + tx] = __float2bfloat16(tile[tx][i]);
}

// ---------- kernel: t = logmap0(expmap0(LN(logmap0(x)))) -> bf16 ----------
__global__ __launch_bounds__(256) void k_t(const float* __restrict__ x,
                                           const float* __restrict__ g1,
                                           const float* __restrict__ beta1,
                                           __hip_bfloat16* __restrict__ t) {
  __shared__ float sbuf[4];
  int r = blockIdx.x, tid = threadIdx.x;
  const float* xr = x + (size_t)r * NP1;
  float xs = xr[1 + tid];
  float ss = block_reduce_sum(xs * xs, sbuf);
  float n1 = fmaxf(sqrtf(ss), EPSF);
  float x0 = fmaxf(xr[0], 1.0f + 1e-7f);
  float lm = acoshf(x0) * xs / n1;
  float mean = block_reduce_sum(lm, sbuf) * (1.0f/256.0f);
  float d = lm - mean;
  float var = block_reduce_sum(d*d, sbuf) * (1.0f/256.0f);
  float u = d * rsqrtf(var + 1e-5f) * g1[tid] + beta1[tid];
  float un = block_reduce_sum(u*u, sbuf);
  float nu = fmaxf(sqrtf(un), EPSF);
  float ch = coshf(nu), sh = sinhf(nu);
  float xs2 = sh * u / nu;
  float ss2 = block_reduce_sum(xs2*xs2, sbuf);
  float n2 = fmaxf(sqrtf(ss2), EPSF);
  float x0c = fmaxf(ch, 1.0f + 1e-7f);
  t[(size_t)r * D_ + tid] = __float2bfloat16(acoshf(x0c) * xs2 / n2);
}

// ---------- bf16 MFMA GEMM: C = act(A @ Bt^T + bias) ----------
// A bf16 [M][K] row-major, Bt bf16 [N][K] row-major (pre-transposed weights).
// M%128==0, N%128==0, K%32==0. 128x128 tile, BK=32, 4 waves (2x2 of 64x64).
// act: 0 none, 1 elu+1, 2 gelu(tanh). outFp32: write float else bf16.
// LDS layout: 64 lines x 128B; line L holds rows {2L,2L+1} as 8 chunks of
// 16B, chunk-swizzled p8 = q ^ (L&7), q = (row&1)*4 + kchunk. Matches
// global_load_lds's forced dest=base+lane*16; frag ds_read_b128 lands 2-way
// bank conflicts (free per m136).
__global__ __launch_bounds__(256) void k_mm(const __hip_bfloat16* __restrict__ A,
                                            const __hip_bfloat16* __restrict__ Bt,
                                            const float* __restrict__ bias,
                                            void* __restrict__ Cout,
                                            int M, int N, int K, int act, int outFp32) {
  __shared__ short As[4096];   // 128 rows x 32 k (swizzled), 8KB
  __shared__ short Bs[4096];
  int tid = threadIdx.x, w = tid >> 6, l = tid & 63;
  int m0 = blockIdx.x * 128, n0 = blockIdx.y * 128;

  // staging: wave w pass p covers lines (2w+p)*8 .. +7
  int offG[2], dstS[2];
#pragma unroll
  for (int p = 0; p < 2; ++p) {
    int L = (w*2 + p)*8 + (l >> 3);
    int q = (l & 7) ^ (L & 7);
    int r = 2*L + (q >> 2);
    int c = q & 3;
    offG[p] = r * K + c * 8;         // element offset
    dstS[p] = (w*2 + p) * 512;       // short offset (1024B per wave-pass)
  }
  const short* Ag = (const short*)A + (size_t)m0 * K;
  const short* Bg = (const short*)Bt + (size_t)n0 * K;

  // fragment LDS offsets
  int ml = l & 15, quad = l >> 4;
  int wm = (w & 1) * 64, wn = (w >> 1) * 64;
  int aoff[4], boff[4];
#pragma unroll
  for (int i = 0; i < 4; ++i) {
    int m = wm + i*16 + ml;
    int L = m >> 1, q = (m & 1)*4 + quad;
    aoff[i] = L*64 + (q ^ (L & 7))*8;
    int n = wn + i*16 + ml;
    int L2 = n >> 1, q2 = (n & 1)*4 + quad;
    boff[i] = L2*64 + (q2 ^ (L2 & 7))*8;
  }

  f32x4 acc[4][4];
#pragma unroll
  for (int i = 0; i < 4; ++i)
#pragma unroll
    for (int j = 0; j < 4; ++j) acc[i][j] = {0.f, 0.f, 0.f, 0.f};

  for (int k0 = 0; k0 < K; k0 += 32) {
    async16(Ag + offG[0] + k0, &As[dstS[0]]);
    async16(Ag + offG[1] + k0, &As[dstS[1]]);
    async16(Bg + offG[0] + k0, &Bs[dstS[0]]);
    async16(Bg + offG[1] + k0, &Bs[dstS[1]]);
    __syncthreads();                 // drain vmcnt, staging visible
    s16x8 af[4], bf[4];
#pragma unroll
    for (int i = 0; i < 4; ++i) af[i] = *(const s16x8*)&As[aoff[i]];
#pragma unroll
    for (int j = 0; j < 4; ++j) bf[j] = *(const s16x8*)&Bs[boff[j]];
#pragma unroll
    for (int i = 0; i < 4; ++i)
#pragma unroll
      for (int j = 0; j < 4; ++j)
        acc[i][j] = __builtin_amdgcn_mfma_f32_16x16x32_bf16(af[i], bf[j], acc[i][j], 0, 0, 0);
    __syncthreads();                 // frag reads done before next staging
  }

#pragma unroll
  for (int j = 0; j < 4; ++j) {
    int col = n0 + wn + j*16 + ml;
    float bj = bias[col];
#pragma unroll
    for (int i = 0; i < 4; ++i) {
#pragma unroll
      for (int rr = 0; rr < 4; ++rr) {
        int row = m0 + wm + i*16 + quad*4 + rr;
        float v = acc[i][j][rr] + bj;
        if (act == 1) v = (v > 0.0f) ? v + 1.0f : __expf(v);
        else if (act == 2) {
          float x3 = v * v * v;
          v = 0.5f * v * (1.0f + tanhf(0.7978845608028654f * (v + 0.044715f * x3)));
        }
        if (outFp32) ((float*)Cout)[(size_t)row * N + col] = v;
        else ((__hip_bfloat16*)Cout)[(size_t)row * N + col] = __float2bfloat16(v);
      }
    }
  }
}

// ---------- kv + ksum per (b,j,h), fp32 accumulate from bf16 ----------
__global__ __launch_bounds__(256) void k_kv(const __hip_bfloat16* __restrict__ pk,
                                            const __hip_bfloat16* __restrict__ v,
                                            float* __restrict__ kv,
                                            float* __restrict__ ksum) {
  __shared__ float spk[8][DH_];
  __shared__ float sv[8][DH_];
  int blk = blockIdx.x;          // (b*J + j)*H + h
  int h = blk & 7;
  int bj = blk >> 3;
  int j = bj % J_;
  int b = bj / J_;
  int tid = threadIdx.x;
  int tt = tid >> 5, dl = tid & 31;
  int dd = tid & 31, k0 = tid >> 5;
  float acc[4] = {0.f, 0.f, 0.f, 0.f};
  float ks = 0.f;
  for (int t0 = 0; t0 < T_; t0 += 8) {
    size_t row = (size_t)(b * T_ + t0 + tt) * J_ + j;
    spk[tt][dl] = __bfloat162float(pk[row * D_ + h * DH_ + dl]);
    sv[tt][dl]  = __bfloat162float(v [row * D_ + h * DH_ + dl]);
    __syncthreads();
#pragma unroll
    for (int q = 0; q < 8; ++q) {
      float vv = sv[q][dd];
#pragma unroll
      for (int m = 0; m < 4; ++m)
        acc[m] = fmaf(spk[q][k0 + (m << 3)], vv, acc[m]);
    }
    if (tid < 32) {
#pragma unroll
      for (int q = 0; q < 8; ++q) ks += spk[q][tid];
    }
    __syncthreads();
  }
#pragma unroll
  for (int m = 0; m < 4; ++m)
    kv[(size_t)blk * (DH_*DH_) + (size_t)(k0 + (m << 3)) * DH_ + dd] = acc[m];
  if (tid < 32) ksum[(size_t)blk * DH_ + tid] = ks;
}

// ---------- attn = (pq @ kv) / (pq @ ksum + eps) -> bf16 ----------
__global__ __launch_bounds__(256) void k_attn(const __hip_bfloat16* __restrict__ pq,
                                              const float* __restrict__ kv,
                                              const float* __restrict__ ksum,
                                              __hip_bfloat16* __restrict__ attn) {
  __shared__ float spq[D_];
  int r = blockIdx.x, tid = threadIdx.x;
  spq[tid] = __bfloat162float(pq[(size_t)r * D_ + tid]);
  __syncthreads();
  int j = r % J_;
  int bt = r / J_;
  int b = bt / T_;
  int h = tid >> 5, dd = tid & 31;
  int bjh = (b * J_ + j) * H_ + h;
  const float* kvp = kv + (size_t)bjh * (DH_*DH_);
  const float* ksp = ksum + (size_t)bjh * DH_;
  float num = 0.f, den = 0.f;
#pragma unroll
  for (int k = 0; k < DH_; ++k) {
    float p = spq[(h << 5) + k];
    num = fmaf(p, kvp[k * DH_ + dd], num);
    den = fmaf(p, ksp[k], den);
  }
  attn[(size_t)r * D_ + tid] = __float2bfloat16(num / (den + EPSF));
}

// ---------- u2 = LN(logmap0(lorentz_residual(x, expmap0(o)))) -> bf16 ----------
__global__ __launch_bounds__(256) void k_u2(const __hip_bfloat16* __restrict__ o,
                                            const float* __restrict__ x,
                                            const float* __restrict__ g2,
                                            const float* __restrict__ beta2,
                                            __hip_bfloat16* __restrict__ u2) {
  __shared__ float sbuf[4];
  int r = blockIdx.x, tid = threadIdx.x;
  const float* xr = x + (size_t)r * NP1;
  float ov = __bfloat162float(o[(size_t)r * D_ + tid]);
  float so = block_reduce_sum(ov * ov, sbuf);
  float no = fmaxf(sqrtf(so), EPSF);
  float ch = coshf(no), sh = sinhf(no);
  float zi = sh * ov / no;
  float mi = xr[1 + tid] + zi;
  float m0 = xr[0] + ch;
  float ssm = block_reduce_sum(mi * mi, sbuf);
  float denom = sqrtf(fmaxf(m0 * m0 - ssm, EPSF));
  float hi = mi / denom;
  float h0 = m0 / denom;
  float h0c = fmaxf(h0, 1.0f + 1e-7f);
  float sh2 = block_reduce_sum(hi * hi, sbuf);
  float nh = fmaxf(sqrtf(sh2), EPSF);
  float lm = acoshf(h0c) * hi / nh;
  float mean = block_reduce_sum(lm, sbuf) * (1.0f/256.0f);
  float d = lm - mean;
  float var = block_reduce_sum(d * d, sbuf) * (1.0f/256.0f);
  u2[(size_t)r * D_ + tid] = __float2bfloat16(d * rsqrtf(var + 1e-5f) * g2[tid] + beta2[tid]);
}

// ---------- out = expmap0(f), f fp32 ----------
__global__ __launch_bounds__(256) void k_out(const float* __restrict__ f,
                                             float* __restrict__ out) {
  __shared__ float sbuf[4];
  int r = blockIdx.x, tid = threadIdx.x;
  float fv = f[(size_t)r * D_ + tid];
  float ss = block_reduce_sum(fv * fv, sbuf);
  float n = fmaxf(sqrtf(ss), EPSF);
  float sh = sinhf(n);
  if (tid == 0) out[(size_t)r * NP1] = coshf(n);
  out[(size_t)r * NP1 + 1 + tid] = sh * fv / n;
}

extern "C" void kernel_launch(void* const* d_in, const int* in_sizes, int n_in,
                              void* d_out, int out_size, void* d_ws, size_t ws_size,
                              hipStream_t stream) {
  const float* x     = (const float*)d_in[0];
  const float* g1    = (const float*)d_in[1];
  const float* beta1 = (const float*)d_in[2];
  const float* Wq    = (const float*)d_in[3];
  const float* Wk    = (const float*)d_in[4];
  const float* Wv    = (const float*)d_in[5];
  const float* Wo    = (const float*)d_in[6];
  const float* bq    = (const float*)d_in[7];
  const float* bk    = (const float*)d_in[8];
  const float* bv    = (const float*)d_in[9];
  const float* bo    = (const float*)d_in[10];
  const float* g2    = (const float*)d_in[11];
  const float* beta2 = (const float*)d_in[12];
  const float* W1    = (const float*)d_in[13];
  const float* bf1   = (const float*)d_in[14];
  const float* W2    = (const float*)d_in[15];
  const float* bf2   = (const float*)d_in[16];
  float* out = (float*)d_out;
  char* ws = (char*)d_ws;

  // ---- workspace layout (bytes) ----
  size_t off = 0;
  __hip_bfloat16* wqT = (__hip_bfloat16*)(ws + off); off += (size_t)D_*D_*2;     // [256][256]
  __hip_bfloat16* wkT = (__hip_bfloat16*)(ws + off); off += (size_t)D_*D_*2;
  __hip_bfloat16* wvT = (__hip_bfloat16*)(ws + off); off += (size_t)D_*D_*2;
  __hip_bfloat16* woT = (__hip_bfloat16*)(ws + off); off += (size_t)D_*D_*2;
  __hip_bfloat16* w1T = (__hip_bfloat16*)(ws + off); off += (size_t)HID_*D_*2;   // [1024][256]
  __hip_bfloat16* w2T = (__hip_bfloat16*)(ws + off); off += (size_t)D_*HID_*2;   // [256][1024]
  float* kvb = (float*)(ws + off); off += (size_t)(B_*J_*H_)*(DH_*DH_)*4;
  float* ksb = (float*)(ws + off); off += (size_t)(B_*J_*H_)*DH_*4;
  off = (off + 255) & ~(size_t)255;
  __hip_bfloat16* tb = (__hip_bfloat16*)(ws + off); off += (size_t)R_*D_*2;
  __hip_bfloat16* qb = (__hip_bfloat16*)(ws + off); size_t qb_off = off - (size_t)R_*D_*2 + (size_t)R_*D_*2; off += (size_t)R_*D_*2;
  __hip_bfloat16* kb = (__hip_bfloat16*)(ws + off); off += (size_t)R_*D_*2;
  __hip_bfloat16* vb = (__hip_bfloat16*)(ws + off); off += (size_t)R_*D_*2;
  __hip_bfloat16* hid = (__hip_bfloat16*)(ws + off); off += (size_t)(R_/2)*HID_*2;
  float* fbuf = (float*)qb;   // fp32 R*256 aliases qb+kb (both consumed by then)
  (void)qb_off;

  dim3 tconv(32, 8);
  k_wconv<<<dim3(D_/32,  D_/32),  tconv, 0, stream>>>(Wq, wqT, D_,  D_);
  k_wconv<<<dim3(D_/32,  D_/32),  tconv, 0, stream>>>(Wk, wkT, D_,  D_);
  k_wconv<<<dim3(D_/32,  D_/32),  tconv, 0, stream>>>(Wv, wvT, D_,  D_);
  k_wconv<<<dim3(D_/32,  D_/32),  tconv, 0, stream>>>(Wo, woT, D_,  D_);
  k_wconv<<<dim3(HID_/32, D_/32), tconv, 0, stream>>>(W1, w1T, D_,  HID_);  // [256][1024] -> [1024][256]
  k_wconv<<<dim3(D_/32, HID_/32), tconv, 0, stream>>>(W2, w2T, HID_, D_);   // [1024][256] -> [256][1024]

  k_t<<<R_, 256, 0, stream>>>(x, g1, beta1, tb);

  dim3 gqkv(R_/128, D_/128);                 // (832, 2)
  k_mm<<<gqkv, 256, 0, stream>>>(tb, wqT, bq, qb, R_, D_, D_, 1, 0);
  k_mm<<<gqkv, 256, 0, stream>>>(tb, wkT, bk, kb, R_, D_, D_, 1, 0);
  k_mm<<<gqkv, 256, 0, stream>>>(tb, wvT, bv, vb, R_, D_, D_, 0, 0);

  k_kv<<<B_*J_*H_, 256, 0, stream>>>(kb, vb, kvb, ksb);
  k_attn<<<R_, 256, 0, stream>>>(qb, kvb, ksb, kb);   // attn -> kb

  k_mm<<<gqkv, 256, 0, stream>>>(kb, woT, bo, vb, R_, D_, D_, 0, 0);  // o -> vb
  k_u2<<<R_, 256, 0, stream>>>(vb, x, g2, beta2, tb);                 // u2 -> tb

  const int Rc = R_ / 2;                     // 53248 rows per MLP chunk
  for (int c = 0; c < 2; ++c) {
    k_mm<<<dim3(Rc/128, HID_/128), 256, 0, stream>>>(
        tb + (size_t)c * Rc * D_, w1T, bf1, hid, Rc, HID_, D_, 2, 0);
    k_mm<<<dim3(Rc/128, D_/128), 256, 0, stream>>>(
        hid, w2T, bf2, fbuf + (size_t)c * Rc * D_, Rc, D_, HID_, 0, 1);
  }

  k_out<<<R_, 256, 0, stream>>>(fbuf, out);
}

// Round 4
// 973.455 us; speedup vs baseline: 5.2826x; 1.6772x over previous
//
#include <hip/hip_runtime.h>
#include <hip/hip_bf16.h>
#include <math.h>

// LorentzTemporalBlock — bf16 MFMA GEMMs + analytically-simplified elementwise.
// B=8,T=512,J=26,D=256,H=8,DH=32,HID=1024. R = 106496 rows (= 832*128).
// Key identities (vs reference):
//  * logmap0(expmap0(u)) == u  =>  t = LN(logmap0(x))
//  * LN(c*v) == LN(v) for c>0  =>  t = LN(xs)          [logmap0(x) = beta*xs]
//    and u2 = LN(xs + sinh(|o|)/|o| * o)               [alpha*ms, alpha>0]
//    (residual: only the 1e-5 var-eps is not scale-invariant: <=2e-4 rel)
// All transcendentals via __expf/__logf hardware paths; elementwise kernels
// are wave-per-row (shuffle reduce, no LDS/barriers).

#define EPSF 1e-6f
#define B_ 8
#define T_ 512
#define J_ 26
#define D_ 256
#define H_ 8
#define DH_ 32
#define HID_ 1024
#define NP1 257
#define R_ (B_*T_*J_)    // 106496

typedef float  f32x4  __attribute__((ext_vector_type(4)));
typedef short  s16x8  __attribute__((ext_vector_type(8)));

// ---------- async global->LDS 16B ----------
__device__ __forceinline__ void async16(const void* g, void* l) {
  __builtin_amdgcn_global_load_lds(
      (const __attribute__((address_space(1))) unsigned int*)g,
      (__attribute__((address_space(3))) unsigned int*)l, 16, 0, 0);
}

// ---------- wave-wide (64 lane) sum, result in all lanes ----------
__device__ __forceinline__ float wave_sum(float v) {
#pragma unroll
  for (int m = 32; m; m >>= 1) v += __shfl_xor(v, m, 64);
  return v;
}

// ---------- weight transpose+convert: W fp32 [K][N] -> Wt bf16 [N][K] ----------
__global__ __launch_bounds__(256) void k_wconv(const float* __restrict__ W,
                                               __hip_bfloat16* __restrict__ Wt,
                                               int K, int N) {
  __shared__ float tile[32][33];
  int n0 = blockIdx.x * 32, k0 = blockIdx.y * 32;
  int tx = threadIdx.x, ty = threadIdx.y;   // (32,8)
#pragma unroll
  for (int i = ty; i < 32; i += 8) tile[i][tx] = W[(size_t)(k0 + i) * N + n0 + tx];
  __syncthreads();
#pragma unroll
  for (int i = ty; i < 32; i += 8)
    Wt[(size_t)(n0 + i) * K + k0 + tx] = __float2bfloat16(tile[tx][i]);
}

// ---------- t = LN(xs)  (wave-per-row; 4 rows per block) ----------
__global__ __launch_bounds__(256) void k_t(const float* __restrict__ x,
                                           const float* __restrict__ g1,
                                           const float* __restrict__ beta1,
                                           __hip_bfloat16* __restrict__ t) {
  int r = blockIdx.x * 4 + (threadIdx.x >> 6);
  int l = threadIdx.x & 63;
  const float* xr = x + (size_t)r * NP1;
  float xs[4];
#pragma unroll
  for (int i = 0; i < 4; ++i) xs[i] = xr[1 + l + 64*i];
  float p1 = xs[0]+xs[1]+xs[2]+xs[3];
  float p2 = xs[0]*xs[0]+xs[1]*xs[1]+xs[2]*xs[2]+xs[3]*xs[3];
  float s1 = wave_sum(p1);
  float s2 = wave_sum(p2);
  float mean = s1 * (1.0f/256.0f);
  float var = s2 * (1.0f/256.0f) - mean*mean;
  float rstd = rsqrtf(var + 1e-5f);
#pragma unroll
  for (int i = 0; i < 4; ++i) {
    int c = l + 64*i;
    t[(size_t)r * D_ + c] = __float2bfloat16((xs[i]-mean)*rstd*g1[c] + beta1[c]);
  }
}

// ---------- bf16 MFMA GEMM: C = act(A @ Bt^T + bias) ----------
// A bf16 [M][K], Bt bf16 [N][K] (pre-transposed). 128x128 tile, BK=32, 4 waves.
// act: 0 none, 1 elu+1, 2 gelu(tanh). outFp32: write float else bf16.
__global__ __launch_bounds__(256) void k_mm(const __hip_bfloat16* __restrict__ A,
                                            const __hip_bfloat16* __restrict__ Bt,
                                            const float* __restrict__ bias,
                                            void* __restrict__ Cout,
                                            int M, int N, int K, int act, int outFp32) {
  __shared__ short As[4096];   // 128 rows x 32 k (swizzled), 8KB
  __shared__ short Bs[4096];
  int tid = threadIdx.x, w = tid >> 6, l = tid & 63;
  int m0 = blockIdx.x * 128, n0 = blockIdx.y * 128;

  int offG[2], dstS[2];
#pragma unroll
  for (int p = 0; p < 2; ++p) {
    int L = (w*2 + p)*8 + (l >> 3);
    int q = (l & 7) ^ (L & 7);
    int r = 2*L + (q >> 2);
    int c = q & 3;
    offG[p] = r * K + c * 8;
    dstS[p] = (w*2 + p) * 512;
  }
  const short* Ag = (const short*)A + (size_t)m0 * K;
  const short* Bg = (const short*)Bt + (size_t)n0 * K;

  int ml = l & 15, quad = l >> 4;
  int wm = (w & 1) * 64, wn = (w >> 1) * 64;
  int aoff[4], boff[4];
#pragma unroll
  for (int i = 0; i < 4; ++i) {
    int m = wm + i*16 + ml;
    int L = m >> 1, q = (m & 1)*4 + quad;
    aoff[i] = L*64 + (q ^ (L & 7))*8;
    int n = wn + i*16 + ml;
    int L2 = n >> 1, q2 = (n & 1)*4 + quad;
    boff[i] = L2*64 + (q2 ^ (L2 & 7))*8;
  }

  f32x4 acc[4][4];
#pragma unroll
  for (int i = 0; i < 4; ++i)
#pragma unroll
    for (int j = 0; j < 4; ++j) acc[i][j] = {0.f, 0.f, 0.f, 0.f};

  for (int k0 = 0; k0 < K; k0 += 32) {
    async16(Ag + offG[0] + k0, &As[dstS[0]]);
    async16(Ag + offG[1] + k0, &As[dstS[1]]);
    async16(Bg + offG[0] + k0, &Bs[dstS[0]]);
    async16(Bg + offG[1] + k0, &Bs[dstS[1]]);
    __syncthreads();
    s16x8 af[4], bf[4];
#pragma unroll
    for (int i = 0; i < 4; ++i) af[i] = *(const s16x8*)&As[aoff[i]];
#pragma unroll
    for (int j = 0; j < 4; ++j) bf[j] = *(const s16x8*)&Bs[boff[j]];
#pragma unroll
    for (int i = 0; i < 4; ++i)
#pragma unroll
      for (int j = 0; j < 4; ++j)
        acc[i][j] = __builtin_amdgcn_mfma_f32_16x16x32_bf16(af[i], bf[j], acc[i][j], 0, 0, 0);
    __syncthreads();
  }

#pragma unroll
  for (int j = 0; j < 4; ++j) {
    int col = n0 + wn + j*16 + ml;
    float bj = bias[col];
#pragma unroll
    for (int i = 0; i < 4; ++i) {
#pragma unroll
      for (int rr = 0; rr < 4; ++rr) {
        int row = m0 + wm + i*16 + quad*4 + rr;
        float v = acc[i][j][rr] + bj;
        if (act == 1) v = (v > 0.0f) ? v + 1.0f : __expf(v);
        else if (act == 2) {
          float xx = 0.7978845608028654f * (v + 0.044715f * v * v * v);
          float th = 1.0f - 2.0f / (__expf(2.0f * xx) + 1.0f);  // tanh(xx), inf-safe
          v = 0.5f * v * (1.0f + th);
        }
        if (outFp32) ((float*)Cout)[(size_t)row * N + col] = v;
        else ((__hip_bfloat16*)Cout)[(size_t)row * N + col] = __float2bfloat16(v);
      }
    }
  }
}

// ---------- kv + ksum per (b,j,h), fp32 accumulate from bf16 ----------
__global__ __launch_bounds__(256) void k_kv(const __hip_bfloat16* __restrict__ pk,
                                            const __hip_bfloat16* __restrict__ v,
                                            float* __restrict__ kv,
                                            float* __restrict__ ksum) {
  __shared__ float spk[8][DH_];
  __shared__ float sv[8][DH_];
  int blk = blockIdx.x;          // (b*J + j)*H + h
  int h = blk & 7;
  int bj = blk >> 3;
  int j = bj % J_;
  int b = bj / J_;
  int tid = threadIdx.x;
  int tt = tid >> 5, dl = tid & 31;
  int dd = tid & 31, k0 = tid >> 5;
  float acc[4] = {0.f, 0.f, 0.f, 0.f};
  float ks = 0.f;
  for (int t0 = 0; t0 < T_; t0 += 8) {
    size_t row = (size_t)(b * T_ + t0 + tt) * J_ + j;
    spk[tt][dl] = __bfloat162float(pk[row * D_ + h * DH_ + dl]);
    sv[tt][dl]  = __bfloat162float(v [row * D_ + h * DH_ + dl]);
    __syncthreads();
#pragma unroll
    for (int q = 0; q < 8; ++q) {
      float vv = sv[q][dd];
#pragma unroll
      for (int m = 0; m < 4; ++m)
        acc[m] = fmaf(spk[q][k0 + (m << 3)], vv, acc[m]);
    }
    if (tid < 32) {
#pragma unroll
      for (int q = 0; q < 8; ++q) ks += spk[q][tid];
    }
    __syncthreads();
  }
#pragma unroll
  for (int m = 0; m < 4; ++m)
    kv[(size_t)blk * (DH_*DH_) + (size_t)(k0 + (m << 3)) * DH_ + dd] = acc[m];
  if (tid < 32) ksum[(size_t)blk * DH_ + tid] = ks;
}

// ---------- attn = (pq @ kv) / (pq @ ksum + eps) -> bf16 ----------
// grid (T/32, B*J). kv column cached in registers (loaded once per block);
// pq rows staged fp32 in LDS (stride 264: 16B-aligned rows + bank rotation).
__global__ __launch_bounds__(256) void k_attn(const __hip_bfloat16* __restrict__ pq,
                                              const float* __restrict__ kv,
                                              const float* __restrict__ ksum,
                                              __hip_bfloat16* __restrict__ attn) {
  __shared__ float psf[32][264];
  __shared__ float dens[32][8];
  int bj = blockIdx.y;           // b*J + j
  int b = bj / J_, j = bj % J_;
  int t0 = blockIdx.x * 32;
  int tid = threadIdx.x, w = tid >> 6, l = tid & 63;
  int h = w*2 + (l >> 5), dd = l & 31;

  const float* kvp = kv + ((size_t)bj * 8 + h) * (DH_*DH_);
  float kvreg[32];
#pragma unroll
  for (int k = 0; k < 32; ++k) kvreg[k] = kvp[k*32 + dd];

  // stage 32 pq rows as fp32
  for (int tr = 0; tr < 32; ++tr) {
    int g = (b * T_ + t0 + tr) * J_ + j;
    psf[tr][tid] = __bfloat162float(pq[(size_t)g * D_ + tid]);
  }
  __syncthreads();

  // dens[tr][h] = dot(pq_row[h], ksum[h])  (one per thread)
  {
    int tr = tid & 31, hh = tid >> 5;
    const float* ksp = ksum + ((size_t)bj * 8 + hh) * DH_;
    float dsum = 0.f;
#pragma unroll
    for (int k = 0; k < 32; ++k) dsum = fmaf(psf[tr][hh*32 + k], ksp[k], dsum);
    dens[tr][hh] = dsum;
  }
  __syncthreads();

  for (int tr = 0; tr < 32; ++tr) {
    const float* pr = &psf[tr][h*32];
    float num = 0.f;
#pragma unroll
    for (int k = 0; k < 32; ++k) num = fmaf(pr[k], kvreg[k], num);
    int g = (b * T_ + t0 + tr) * J_ + j;
    attn[(size_t)g * D_ + tid] = __float2bfloat16(num / (dens[tr][h] + EPSF));
  }
}

// ---------- u2 = LN(xs + sinh(|o|)/|o| * o)  (wave-per-row) ----------
__global__ __launch_bounds__(256) void k_u2(const __hip_bfloat16* __restrict__ o,
                                            const float* __restrict__ x,
                                            const float* __restrict__ g2,
                                            const float* __restrict__ beta2,
                                            __hip_bfloat16* __restrict__ u2) {
  int r = blockIdx.x * 4 + (threadIdx.x >> 6);
  int l = threadIdx.x & 63;
  const float* xr = x + (size_t)r * NP1;
  float ov[4], xs[4];
#pragma unroll
  for (int i = 0; i < 4; ++i) {
    ov[i] = __bfloat162float(o[(size_t)r * D_ + l + 64*i]);
    xs[i] = xr[1 + l + 64*i];
  }
  float p2 = ov[0]*ov[0]+ov[1]*ov[1]+ov[2]*ov[2]+ov[3]*ov[3];
  float s2o = wave_sum(p2);
  float no = fmaxf(sqrtf(s2o), EPSF);
  float e = __expf(no);
  float c = (e - 1.0f/e) * 0.5f / no;      // sinh(no)/no
  float mi[4];
#pragma unroll
  for (int i = 0; i < 4; ++i) mi[i] = xs[i] + c * ov[i];
  float q1 = mi[0]+mi[1]+mi[2]+mi[3];
  float q2 = mi[0]*mi[0]+mi[1]*mi[1]+mi[2]*mi[2]+mi[3]*mi[3];
  float s1 = wave_sum(q1);
  float s2 = wave_sum(q2);
  float mean = s1 * (1.0f/256.0f);
  float var = s2 * (1.0f/256.0f) - mean*mean;
  float rstd = rsqrtf(var + 1e-5f);
#pragma unroll
  for (int i = 0; i < 4; ++i) {
    int cc = l + 64*i;
    u2[(size_t)r * D_ + cc] = __float2bfloat16((mi[i]-mean)*rstd*g2[cc] + beta2[cc]);
  }
}

// ---------- out = expmap0(f), f fp32  (wave-per-row) ----------
__global__ __launch_bounds__(256) void k_out(const float* __restrict__ f,
                                             float* __restrict__ out) {
  int r = blockIdx.x * 4 + (threadIdx.x >> 6);
  int l = threadIdx.x & 63;
  const float* fr = f + (size_t)r * D_;
  float fv[4];
#pragma unroll
  for (int i = 0; i < 4; ++i) fv[i] = fr[l + 64*i];
  float p2 = fv[0]*fv[0]+fv[1]*fv[1]+fv[2]*fv[2]+fv[3]*fv[3];
  float s2 = wave_sum(p2);
  float n = fmaxf(sqrtf(s2), EPSF);
  float e = __expf(n);
  float ie = 1.0f / e;
  float sh = (e - ie) * 0.5f;
  float ch = (e + ie) * 0.5f;
  float s = sh / n;
  float* orow = out + (size_t)r * NP1;
  if (l == 0) orow[0] = ch;
#pragma unroll
  for (int i = 0; i < 4; ++i) orow[1 + l + 64*i] = s * fv[i];
}

extern "C" void kernel_launch(void* const* d_in, const int* in_sizes, int n_in,
                              void* d_out, int out_size, void* d_ws, size_t ws_size,
                              hipStream_t stream) {
  const float* x     = (const float*)d_in[0];
  const float* g1    = (const float*)d_in[1];
  const float* beta1 = (const float*)d_in[2];
  const float* Wq    = (const float*)d_in[3];
  const float* Wk    = (const float*)d_in[4];
  const float* Wv    = (const float*)d_in[5];
  const float* Wo    = (const float*)d_in[6];
  const float* bq    = (const float*)d_in[7];
  const float* bk    = (const float*)d_in[8];
  const float* bv    = (const float*)d_in[9];
  const float* bo    = (const float*)d_in[10];
  const float* g2    = (const float*)d_in[11];
  const float* beta2 = (const float*)d_in[12];
  const float* W1    = (const float*)d_in[13];
  const float* bf1   = (const float*)d_in[14];
  const float* W2    = (const float*)d_in[15];
  const float* bf2   = (const float*)d_in[16];
  float* out = (float*)d_out;
  char* ws = (char*)d_ws;

  // ---- workspace layout (bytes) ----
  size_t off = 0;
  __hip_bfloat16* wqT = (__hip_bfloat16*)(ws + off); off += (size_t)D_*D_*2;
  __hip_bfloat16* wkT = (__hip_bfloat16*)(ws + off); off += (size_t)D_*D_*2;
  __hip_bfloat16* wvT = (__hip_bfloat16*)(ws + off); off += (size_t)D_*D_*2;
  __hip_bfloat16* woT = (__hip_bfloat16*)(ws + off); off += (size_t)D_*D_*2;
  __hip_bfloat16* w1T = (__hip_bfloat16*)(ws + off); off += (size_t)HID_*D_*2;
  __hip_bfloat16* w2T = (__hip_bfloat16*)(ws + off); off += (size_t)D_*HID_*2;
  float* kvb = (float*)(ws + off); off += (size_t)(B_*J_*H_)*(DH_*DH_)*4;
  float* ksb = (float*)(ws + off); off += (size_t)(B_*J_*H_)*DH_*4;
  off = (off + 255) & ~(size_t)255;
  __hip_bfloat16* tb = (__hip_bfloat16*)(ws + off); off += (size_t)R_*D_*2;
  __hip_bfloat16* qb = (__hip_bfloat16*)(ws + off); off += (size_t)R_*D_*2;
  __hip_bfloat16* kb = (__hip_bfloat16*)(ws + off); off += (size_t)R_*D_*2;
  __hip_bfloat16* vb = (__hip_bfloat16*)(ws + off); off += (size_t)R_*D_*2;
  __hip_bfloat16* hid = (__hip_bfloat16*)(ws + off); off += (size_t)(R_/2)*HID_*2;
  float* fbuf = (float*)qb;   // fp32 R*256 aliases qb+kb (both consumed by then)

  dim3 tconv(32, 8);
  k_wconv<<<dim3(D_/32,  D_/32),  tconv, 0, stream>>>(Wq, wqT, D_,  D_);
  k_wconv<<<dim3(D_/32,  D_/32),  tconv, 0, stream>>>(Wk, wkT, D_,  D_);
  k_wconv<<<dim3(D_/32,  D_/32),  tconv, 0, stream>>>(Wv, wvT, D_,  D_);
  k_wconv<<<dim3(D_/32,  D_/32),  tconv, 0, stream>>>(Wo, woT, D_,  D_);
  k_wconv<<<dim3(HID_/32, D_/32), tconv, 0, stream>>>(W1, w1T, D_,  HID_);
  k_wconv<<<dim3(D_/32, HID_/32), tconv, 0, stream>>>(W2, w2T, HID_, D_);

  k_t<<<R_/4, 256, 0, stream>>>(x, g1, beta1, tb);

  dim3 gqkv(R_/128, D_/128);                 // (832, 2)
  k_mm<<<gqkv, 256, 0, stream>>>(tb, wqT, bq, qb, R_, D_, D_, 1, 0);
  k_mm<<<gqkv, 256, 0, stream>>>(tb, wkT, bk, kb, R_, D_, D_, 1, 0);
  k_mm<<<gqkv, 256, 0, stream>>>(tb, wvT, bv, vb, R_, D_, D_, 0, 0);

  k_kv<<<B_*J_*H_, 256, 0, stream>>>(kb, vb, kvb, ksb);
  k_attn<<<dim3(T_/32, B_*J_), 256, 0, stream>>>(qb, kvb, ksb, kb);   // attn -> kb

  k_mm<<<gqkv, 256, 0, stream>>>(kb, woT, bo, vb, R_, D_, D_, 0, 0);  // o -> vb
  k_u2<<<R_/4, 256, 0, stream>>>(vb, x, g2, beta2, tb);               // u2 -> tb

  const int Rc = R_ / 2;                     // 53248 rows per MLP chunk
  for (int c = 0; c < 2; ++c) {
    k_mm<<<dim3(Rc/128, HID_/128), 256, 0, stream>>>(
        tb + (size_t)c * Rc * D_, w1T, bf1, hid, Rc, HID_, D_, 2, 0);
    k_mm<<<dim3(Rc/128, D_/128), 256, 0, stream>>>(
        hid, w2T, bf2, fbuf + (size_t)c * Rc * D_, Rc, D_, HID_, 0, 1);
  }

  k_out<<<R_/4, 256, 0, stream>>>(fbuf, out);
}